// Round 11
// baseline (244.784 us; speedup 1.0000x reference)
//
#include <hip/hip_runtime.h>

// Problem: B=4, S=2048, H=16, D=64, E=1024. Inputs fp32, output fp32.
// out = proj( attention( cos(x+theta) ) )  with Q==K==V per head.
//
// Round 19: attn reverted to r9-best (91us: fused exp/pack, K=32 PV via Pb
// LDS, 32KB, between-barrier staging). K=16 PV refuted (r10: mfma16 issues
// at mfma32 cost -> PV MFMA time doubled, MfmaUtil 32->47, time flat).
// This round targets the never-profiled ~105us prep+proj tail:
//  proj: (a) XCD swizzle - each XCD owns an 8x8 block patch => A-strip 2MB
//        + full Wb 2MB L2-resident; (b) T14 reg prefetch of next kc tile
//        (32 VGPR, safe at (256,2) = 256-reg cap); epilogue unchanged.
// ws: [0,16M) qkv  [16M,32M) qkvT  [32M,48M) aout  [48M,50M) Wbf.

#define B_  4
#define S_  2048
#define H_  16
#define D_  64
#define E_  1024
// exp(s/8) = exp2(s * log2(e)/8); folded into Q fragments
#define EXP2_SCALE 0.18033688011112043f

typedef unsigned short u16;
typedef unsigned int u32;
typedef __attribute__((ext_vector_type(8))) short short8;
typedef __attribute__((ext_vector_type(4))) float floatx4;

static __device__ __forceinline__ float bf2f(u16 v) {
    return __uint_as_float(((unsigned)v) << 16);
}
static __device__ __forceinline__ u16 f2bf(float f) {
    unsigned u = __float_as_uint(f);
    return (u16)((u + 0x7FFFu + ((u >> 16) & 1u)) >> 16);
}
// pack bf16(lo),bf16(hi) from two f32 by truncation: 1 v_perm_b32
static __device__ __forceinline__ u32 pack_bf16_trunc(float lo, float hi) {
    return __builtin_amdgcn_perm(__float_as_uint(hi), __float_as_uint(lo), 0x07060302u);
}
// unpack-scale-repack a short8 of bf16 by EXP2_SCALE (one-time, RNE)
static __device__ __forceinline__ short8 scale8(short8 v) {
    short8 o;
#pragma unroll
    for (int i = 0; i < 8; i++)
        o[i] = (short)f2bf(bf2f((u16)v[i]) * EXP2_SCALE);
    return o;
}

// XOR-swizzled element offset within a [rows][64] u16 LDS tile.
// Valid for 16B (8-elem) and 8B (4-elem) aligned accesses.
#define KSWZ(r, c) ((((r)) << 6) + (((c) ^ ((((r)) & 7) << 3))))

// ---------------------------------------------------------------------------
// Kernel 1 (fused prep):
//  blocks [0,2048):   qkv[bh][s][d] = cos(x+theta) bf16, qkvT = transpose
//  blocks [2048,3072): Wbf = bf16(W)
// ---------------------------------------------------------------------------
__global__ __launch_bounds__(256) void prep_kernel(const float* __restrict__ x,
                                                   const float* __restrict__ theta,
                                                   const float* __restrict__ W,
                                                   u16* __restrict__ qkv,
                                                   u16* __restrict__ qkvT,
                                                   u16* __restrict__ Wb) {
    __shared__ __align__(16) u16 TQ[64][72];
    int blk = blockIdx.x;
    int tid = threadIdx.x;
    if (blk >= 2048) {  // wconv part
        int i = ((blk - 2048) * 256 + tid) * 4;
        float4 w = *(const float4*)(W + i);
        ushort4 o;
        o.x = f2bf(w.x); o.y = f2bf(w.y); o.z = f2bf(w.z); o.w = f2bf(w.w);
        *(ushort4*)(Wb + i) = o;
        return;
    }
    int stile = blk & 31;
    int bh    = blk >> 5;
    int b     = bh >> 4;
    int h     = bh & 15;
    int i     = tid >> 2;
    int d0    = (tid & 3) << 4;
    int s0    = stile << 6;
    int s     = s0 + i;

    const float* xp = x + ((size_t)(b * S_ + s)) * E_ + h * D_ + d0;
    const float* tp = theta + h * D_ + d0;

    u16 ov[16];
#pragma unroll
    for (int j = 0; j < 16; j += 4) {
        float4 xv = *(const float4*)(xp + j);
        float4 tv = *(const float4*)(tp + j);
        ov[j]     = f2bf(__cosf(xv.x + tv.x));
        ov[j + 1] = f2bf(__cosf(xv.y + tv.y));
        ov[j + 2] = f2bf(__cosf(xv.z + tv.z));
        ov[j + 3] = f2bf(__cosf(xv.w + tv.w));
    }

    u16* qp = qkv + ((size_t)bh * S_ + s) * D_ + d0;
    *(uint4*)qp       = *(uint4*)&ov[0];
    *(uint4*)(qp + 8) = *(uint4*)&ov[8];

#pragma unroll
    for (int j = 0; j < 16; j++) TQ[d0 + j][i] = ov[j];
    __syncthreads();

    int d  = tid >> 2;
    int j0 = (tid & 3) << 4;
    u16 tmp[16];
#pragma unroll
    for (int j = 0; j < 16; j++) tmp[j] = TQ[d][j0 + j];
    u16* qtp = qkvT + ((size_t)bh * D_ + d) * S_ + s0 + j0;
    *(uint4*)qtp       = *(uint4*)&tmp[0];
    *(uint4*)(qtp + 8) = *(uint4*)&tmp[8];
}

// ---------------------------------------------------------------------------
// Kernel 2: flash attention per (bh, 128-q-tile), S^T formulation.
// == round-9 best (91us): 4 waves; QK^T t-loop fused with exp/pack/P-write;
// Pb LDS round-trip; K=32 MFMA everywhere; between-barrier staging.
// ---------------------------------------------------------------------------
__global__ __launch_bounds__(256, 4) void attn_kernel(const u16* __restrict__ qkv,
                                                      const u16* __restrict__ qkvT,
                                                      u16* __restrict__ aout) {
    int blk0 = blockIdx.x;
    int blk  = (blk0 & 7) * 128 + (blk0 >> 3);
    int qt   = blk & 15;
    int bh   = blk >> 4;
    int b    = bh >> 4;
    int h    = bh & 15;
    int tid  = threadIdx.x;
    int wave = tid >> 6;
    int lane = tid & 63;
    int lq   = lane & 15;
    int lg   = lane >> 4;
    int r    = tid >> 2;
    int c0   = (tid & 3) << 4;

    __shared__ __align__(16) u16 Kt[64 * 64];      // K tile [key][d], swizzled
    __shared__ __align__(16) u16 Vt[64 * 64];      // V^T tile [d][key], swizzled
    __shared__ __align__(16) u16 Pb[4][32 * 64];   // per-wave P [q][key], swizzled

    const u16* base  = qkv  + (size_t)bh * S_ * D_;
    const u16* baseT = qkvT + (size_t)bh * D_ * S_;
    int s0 = qt * 128;

    short8 bq[2][2];
#pragma unroll
    for (int rf = 0; rf < 2; rf++) {
        const u16* qrow = base + (size_t)(s0 + wave * 32 + rf * 16 + lq) * D_ + lg * 8;
        bq[rf][0] = scale8(*(const short8*)qrow);
        bq[rf][1] = scale8(*(const short8*)(qrow + 32));
    }

    floatx4 oacc[2][4] = {{{0,0,0,0},{0,0,0,0},{0,0,0,0},{0,0,0,0}},
                          {{0,0,0,0},{0,0,0,0},{0,0,0,0},{0,0,0,0}}};
    float lsum[2] = {0.f, 0.f};

    // prologue: stage tile 0
    {
        const u16* p = base + (size_t)r * D_ + c0;
        *(uint4*)&Kt[KSWZ(r, c0)]     = *(const uint4*)p;
        *(uint4*)&Kt[KSWZ(r, c0 + 8)] = *(const uint4*)(p + 8);
        const u16* p2 = baseT + (size_t)r * S_ + c0;
        *(uint4*)&Vt[KSWZ(r, c0)]     = *(const uint4*)p2;
        *(uint4*)&Vt[KSWZ(r, c0 + 8)] = *(const uint4*)(p2 + 8);
    }
    __syncthreads();

    for (int kt = 0; kt < S_ / 64; kt++) {
        // QK^T fused with exp/pack/P-write: only sct[2] (8 regs) live.
#pragma unroll
        for (int t = 0; t < 4; t++) {
            short8 a0 = *(short8*)&Kt[KSWZ(t * 16 + lq, lg * 8)];
            short8 a1 = *(short8*)&Kt[KSWZ(t * 16 + lq, 32 + lg * 8)];
            floatx4 sct[2];
#pragma unroll
            for (int rf = 0; rf < 2; rf++) {
                floatx4 acc = {0, 0, 0, 0};
                acc = __builtin_amdgcn_mfma_f32_16x16x32_bf16(a0, bq[rf][0], acc, 0, 0, 0);
                sct[rf] = __builtin_amdgcn_mfma_f32_16x16x32_bf16(a1, bq[rf][1], acc, 0, 0, 0);
            }
#pragma unroll
            for (int rf = 0; rf < 2; rf++) {
                float p0 = __builtin_amdgcn_exp2f(sct[rf][0]);
                float p1 = __builtin_amdgcn_exp2f(sct[rf][1]);
                float p2 = __builtin_amdgcn_exp2f(sct[rf][2]);
                float p3 = __builtin_amdgcn_exp2f(sct[rf][3]);
                lsum[rf] += (p0 + p1) + (p2 + p3);
                uint2 w;
                w.x = pack_bf16_trunc(p0, p1);
                w.y = pack_bf16_trunc(p2, p3);
                *(uint2*)&Pb[wave][KSWZ(rf * 16 + lq, t * 16 + lg * 4)] = w;
            }
        }

        // per-wave DS in-order: drain P writes before dependent reads
        asm volatile("s_waitcnt lgkmcnt(0)" ::: "memory");

        // O^T += V^T · P^T : A = Vt rows (d), B = Pb rows (q)
        short8 bp[2][2];
#pragma unroll
        for (int rf = 0; rf < 2; rf++) {
            bp[rf][0] = *(short8*)&Pb[wave][KSWZ(rf * 16 + lq, lg * 8)];
            bp[rf][1] = *(short8*)&Pb[wave][KSWZ(rf * 16 + lq, 32 + lg * 8)];
        }
        __builtin_amdgcn_s_setprio(1);
#pragma unroll
        for (int t = 0; t < 4; t++) {
            short8 av0 = *(short8*)&Vt[KSWZ(t * 16 + lq, lg * 8)];
            short8 av1 = *(short8*)&Vt[KSWZ(t * 16 + lq, 32 + lg * 8)];
#pragma unroll
            for (int rf = 0; rf < 2; rf++) {
                oacc[rf][t] = __builtin_amdgcn_mfma_f32_16x16x32_bf16(av0, bp[rf][0], oacc[rf][t], 0, 0, 0);
                oacc[rf][t] = __builtin_amdgcn_mfma_f32_16x16x32_bf16(av1, bp[rf][1], oacc[rf][t], 0, 0, 0);
            }
        }
        __builtin_amdgcn_s_setprio(0);

        __syncthreads();  // all waves done reading Kt/Vt of tile kt
        if (kt < S_ / 64 - 1) {
            const u16* p = base + (size_t)((kt + 1) * 64 + r) * D_ + c0;
            uint4 k0 = *(const uint4*)p;
            uint4 k1 = *(const uint4*)(p + 8);
            const u16* p2 = baseT + (size_t)r * S_ + (kt + 1) * 64 + c0;
            uint4 v0 = *(const uint4*)p2;
            uint4 v1 = *(const uint4*)(p2 + 8);
            *(uint4*)&Kt[KSWZ(r, c0)]     = k0;
            *(uint4*)&Kt[KSWZ(r, c0 + 8)] = k1;
            *(uint4*)&Vt[KSWZ(r, c0)]     = v0;
            *(uint4*)&Vt[KSWZ(r, c0 + 8)] = v1;
        }
        __syncthreads();  // tile kt+1 visible
    }

    // reduce lsum across the 4 lane-quads holding the same q
#pragma unroll
    for (int rf = 0; rf < 2; rf++) {
        lsum[rf] += __shfl_xor(lsum[rf], 16);
        lsum[rf] += __shfl_xor(lsum[rf], 32);
    }
    // epilogue: O^T lane (q=lq, d=16t+4lg+rr) -> aout[b][q][h*64+d] (RNE)
#pragma unroll
    for (int rf = 0; rf < 2; rf++) {
        float inv = 1.0f / fmaxf(lsum[rf], 1e-20f);
        int srow = s0 + wave * 32 + rf * 16 + lq;
        u16* arow = aout + ((size_t)(b * S_ + srow)) * E_ + h * D_;
#pragma unroll
        for (int t = 0; t < 4; t++)
#pragma unroll
            for (int rr = 0; rr < 4; rr++)
                arow[t * 16 + lg * 4 + rr] = f2bf(oacc[rf][t][rr] * inv);
    }
}

// ---------------------------------------------------------------------------
// Kernel 3: out[8192][1024] = AO * Wb^T + bias (fp32 out). Wb bf16 [n][k].
// 128x128 tile per block, 4 waves 2x2. Round 19: XCD swizzle (each XCD owns
// an 8x8 block patch: A-strip 2MB + Wb 2MB L2-resident) + T14 reg prefetch
// of next kc tile. (256,2): 256-reg cap, ~140 live, no spill.
// ---------------------------------------------------------------------------
__global__ __launch_bounds__(256, 2) void proj_kernel(const u16* __restrict__ A,
                                                      const u16* __restrict__ Wb,
                                                      const float* __restrict__ bias,
                                                      float* __restrict__ out) {
    // XCD swizzle: grid is 1D 512. XCD k = b0&7 gets x-strip [8k,8k+8) x all y.
    int b0 = blockIdx.x;
    int xk = b0 & 7;
    int rr_ = b0 >> 3;              // 0..63
    int xb = xk * 8 + (rr_ & 7);    // m-block 0..63
    int yb = rr_ >> 3;              // n-block 0..7
    int m0 = xb * 128;
    int n0 = yb * 128;

    int tid  = threadIdx.x;
    int wave = tid >> 6;
    int wm   = wave >> 1;
    int wn   = wave & 1;
    int lane = tid & 63;
    int lq   = lane & 15;
    int lg   = lane >> 4;
    int row  = tid >> 1;
    int c0   = (tid & 1) * 32;

    __shared__ __align__(16) u16 As[128][72];
    __shared__ __align__(16) u16 Bs[128][72];

    floatx4 acc[4][4];
#pragma unroll
    for (int i = 0; i < 4; i++)
#pragma unroll
        for (int j = 0; j < 4; j++) acc[i][j] = (floatx4){0, 0, 0, 0};

    const u16* pa0 = A  + (size_t)(m0 + row) * E_ + c0;
    const u16* pw0 = Wb + (size_t)(n0 + row) * E_ + c0;

    // prologue: stage kc=0
#pragma unroll
    for (int j = 0; j < 4; j++) {
        *(uint4*)&As[row][c0 + j * 8] = *(const uint4*)(pa0 + j * 8);
        *(uint4*)&Bs[row][c0 + j * 8] = *(const uint4*)(pw0 + j * 8);
    }
    __syncthreads();

    for (int kc = 0; kc < E_; kc += 64) {
        // T14: issue next-tile loads before compute; latency hides under MFMA.
        uint4 na[4], nb[4];
        if (kc + 64 < E_) {
#pragma unroll
            for (int j = 0; j < 4; j++) {
                na[j] = *(const uint4*)(pa0 + kc + 64 + j * 8);
                nb[j] = *(const uint4*)(pw0 + kc + 64 + j * 8);
            }
        }

#pragma unroll
        for (int c = 0; c < 2; c++) {
            short8 af[4], bf[4];
#pragma unroll
            for (int i = 0; i < 4; i++)
                af[i] = *(short8*)&As[wm * 64 + i * 16 + lq][c * 32 + lg * 8];
#pragma unroll
            for (int j = 0; j < 4; j++)
                bf[j] = *(short8*)&Bs[wn * 64 + j * 16 + lq][c * 32 + lg * 8];
#pragma unroll
            for (int i = 0; i < 4; i++)
#pragma unroll
                for (int j = 0; j < 4; j++)
                    acc[i][j] = __builtin_amdgcn_mfma_f32_16x16x32_bf16(af[i], bf[j], acc[i][j], 0, 0, 0);
        }

        __syncthreads();
        if (kc + 64 < E_) {
#pragma unroll
            for (int j = 0; j < 4; j++) {
                *(uint4*)&As[row][c0 + j * 8] = na[j];
                *(uint4*)&Bs[row][c0 + j * 8] = nb[j];
            }
        }
        __syncthreads();
    }

#pragma unroll
    for (int j = 0; j < 4; j++) {
        int nidx = n0 + wn * 64 + j * 16 + lq;
        float bv = bias[nidx];
#pragma unroll
        for (int i = 0; i < 4; i++) {
#pragma unroll
            for (int rr = 0; rr < 4; rr++) {
                int orow = m0 + wm * 64 + i * 16 + lg * 4 + rr;
                out[(size_t)orow * E_ + nidx] = acc[i][j][rr] + bv;
            }
        }
    }
}

// ---------------------------------------------------------------------------
extern "C" void kernel_launch(void* const* d_in, const int* in_sizes, int n_in,
                              void* d_out, int out_size, void* d_ws, size_t ws_size,
                              hipStream_t stream) {
    const float* x     = (const float*)d_in[0];
    const float* theta = (const float*)d_in[1];
    const float* w_out = (const float*)d_in[2];
    const float* b_out = (const float*)d_in[3];
    float* out = (float*)d_out;

    char* ws = (char*)d_ws;
    const size_t QKV_BYTES = (size_t)B_ * H_ * S_ * D_ * sizeof(u16);  // 16 MiB
    u16* qkv  = (u16*)ws;
    u16* qkvT = (u16*)(ws + QKV_BYTES);
    u16* aout = (u16*)(ws + 2 * QKV_BYTES);
    u16* wbf_safe = (u16*)(ws + 3 * QKV_BYTES);

    prep_kernel<<<3072, 256, 0, stream>>>(x, theta, w_out, qkv, qkvT, wbf_safe);
    attn_kernel<<<(B_ * H_) * (S_ / 128), 256, 0, stream>>>(qkv, qkvT, aout);
    proj_kernel<<<512, 256, 0, stream>>>(aout, wbf_safe, b_out, out);
}

// Round 12
// 222.351 us; speedup vs baseline: 1.1009x; 1.1009x over previous
//
#include <hip/hip_runtime.h>

// Problem: B=4, S=2048, H=16, D=64, E=1024. Inputs fp32, output fp32.
// out = proj( attention( cos(x+theta) ) )  with Q==K==V per head.
//
// Round 20: single-variable round. r11 proved (by subtraction) that its
// bundled proj change (1D swizzle + prefetch + (256,2)) cost ~49us via
// occupancy loss (2 blocks/CU). Revert proj to r9 body + 2D grid; ONLY
// change: __launch_bounds__(256,3) -> 170-reg cap (live ~143, no spill),
// guaranteeing 3 blocks/CU. attn frozen at r9-best (90.8us measured).
// ws: [0,16M) qkv  [16M,32M) qkvT  [32M,48M) aout  [48M,50M) Wbf.

#define B_  4
#define S_  2048
#define H_  16
#define D_  64
#define E_  1024
// exp(s/8) = exp2(s * log2(e)/8); folded into Q fragments
#define EXP2_SCALE 0.18033688011112043f

typedef unsigned short u16;
typedef unsigned int u32;
typedef __attribute__((ext_vector_type(8))) short short8;
typedef __attribute__((ext_vector_type(4))) float floatx4;

static __device__ __forceinline__ float bf2f(u16 v) {
    return __uint_as_float(((unsigned)v) << 16);
}
static __device__ __forceinline__ u16 f2bf(float f) {
    unsigned u = __float_as_uint(f);
    return (u16)((u + 0x7FFFu + ((u >> 16) & 1u)) >> 16);
}
// pack bf16(lo),bf16(hi) from two f32 by truncation: 1 v_perm_b32
static __device__ __forceinline__ u32 pack_bf16_trunc(float lo, float hi) {
    return __builtin_amdgcn_perm(__float_as_uint(hi), __float_as_uint(lo), 0x07060302u);
}
// unpack-scale-repack a short8 of bf16 by EXP2_SCALE (one-time, RNE)
static __device__ __forceinline__ short8 scale8(short8 v) {
    short8 o;
#pragma unroll
    for (int i = 0; i < 8; i++)
        o[i] = (short)f2bf(bf2f((u16)v[i]) * EXP2_SCALE);
    return o;
}

// XOR-swizzled element offset within a [rows][64] u16 LDS tile.
// Valid for 16B (8-elem) and 8B (4-elem) aligned accesses.
#define KSWZ(r, c) ((((r)) << 6) + (((c) ^ ((((r)) & 7) << 3))))

// ---------------------------------------------------------------------------
// Kernel 1 (fused prep):
//  blocks [0,2048):   qkv[bh][s][d] = cos(x+theta) bf16, qkvT = transpose
//  blocks [2048,3072): Wbf = bf16(W)
// ---------------------------------------------------------------------------
__global__ __launch_bounds__(256) void prep_kernel(const float* __restrict__ x,
                                                   const float* __restrict__ theta,
                                                   const float* __restrict__ W,
                                                   u16* __restrict__ qkv,
                                                   u16* __restrict__ qkvT,
                                                   u16* __restrict__ Wb) {
    __shared__ __align__(16) u16 TQ[64][72];
    int blk = blockIdx.x;
    int tid = threadIdx.x;
    if (blk >= 2048) {  // wconv part
        int i = ((blk - 2048) * 256 + tid) * 4;
        float4 w = *(const float4*)(W + i);
        ushort4 o;
        o.x = f2bf(w.x); o.y = f2bf(w.y); o.z = f2bf(w.z); o.w = f2bf(w.w);
        *(ushort4*)(Wb + i) = o;
        return;
    }
    int stile = blk & 31;
    int bh    = blk >> 5;
    int b     = bh >> 4;
    int h     = bh & 15;
    int i     = tid >> 2;
    int d0    = (tid & 3) << 4;
    int s0    = stile << 6;
    int s     = s0 + i;

    const float* xp = x + ((size_t)(b * S_ + s)) * E_ + h * D_ + d0;
    const float* tp = theta + h * D_ + d0;

    u16 ov[16];
#pragma unroll
    for (int j = 0; j < 16; j += 4) {
        float4 xv = *(const float4*)(xp + j);
        float4 tv = *(const float4*)(tp + j);
        ov[j]     = f2bf(__cosf(xv.x + tv.x));
        ov[j + 1] = f2bf(__cosf(xv.y + tv.y));
        ov[j + 2] = f2bf(__cosf(xv.z + tv.z));
        ov[j + 3] = f2bf(__cosf(xv.w + tv.w));
    }

    u16* qp = qkv + ((size_t)bh * S_ + s) * D_ + d0;
    *(uint4*)qp       = *(uint4*)&ov[0];
    *(uint4*)(qp + 8) = *(uint4*)&ov[8];

#pragma unroll
    for (int j = 0; j < 16; j++) TQ[d0 + j][i] = ov[j];
    __syncthreads();

    int d  = tid >> 2;
    int j0 = (tid & 3) << 4;
    u16 tmp[16];
#pragma unroll
    for (int j = 0; j < 16; j++) tmp[j] = TQ[d][j0 + j];
    u16* qtp = qkvT + ((size_t)bh * D_ + d) * S_ + s0 + j0;
    *(uint4*)qtp       = *(uint4*)&tmp[0];
    *(uint4*)(qtp + 8) = *(uint4*)&tmp[8];
}

// ---------------------------------------------------------------------------
// Kernel 2: flash attention per (bh, 128-q-tile), S^T formulation.
// == round-9 best (90.8us): 4 waves; QK^T fused with exp/pack/P-write;
// Pb LDS round-trip; K=32 MFMA everywhere; between-barrier staging.
// ---------------------------------------------------------------------------
__global__ __launch_bounds__(256, 4) void attn_kernel(const u16* __restrict__ qkv,
                                                      const u16* __restrict__ qkvT,
                                                      u16* __restrict__ aout) {
    int blk0 = blockIdx.x;
    int blk  = (blk0 & 7) * 128 + (blk0 >> 3);
    int qt   = blk & 15;
    int bh   = blk >> 4;
    int b    = bh >> 4;
    int h    = bh & 15;
    int tid  = threadIdx.x;
    int wave = tid >> 6;
    int lane = tid & 63;
    int lq   = lane & 15;
    int lg   = lane >> 4;
    int r    = tid >> 2;
    int c0   = (tid & 3) << 4;

    __shared__ __align__(16) u16 Kt[64 * 64];      // K tile [key][d], swizzled
    __shared__ __align__(16) u16 Vt[64 * 64];      // V^T tile [d][key], swizzled
    __shared__ __align__(16) u16 Pb[4][32 * 64];   // per-wave P [q][key], swizzled

    const u16* base  = qkv  + (size_t)bh * S_ * D_;
    const u16* baseT = qkvT + (size_t)bh * D_ * S_;
    int s0 = qt * 128;

    short8 bq[2][2];
#pragma unroll
    for (int rf = 0; rf < 2; rf++) {
        const u16* qrow = base + (size_t)(s0 + wave * 32 + rf * 16 + lq) * D_ + lg * 8;
        bq[rf][0] = scale8(*(const short8*)qrow);
        bq[rf][1] = scale8(*(const short8*)(qrow + 32));
    }

    floatx4 oacc[2][4] = {{{0,0,0,0},{0,0,0,0},{0,0,0,0},{0,0,0,0}},
                          {{0,0,0,0},{0,0,0,0},{0,0,0,0},{0,0,0,0}}};
    float lsum[2] = {0.f, 0.f};

    // prologue: stage tile 0
    {
        const u16* p = base + (size_t)r * D_ + c0;
        *(uint4*)&Kt[KSWZ(r, c0)]     = *(const uint4*)p;
        *(uint4*)&Kt[KSWZ(r, c0 + 8)] = *(const uint4*)(p + 8);
        const u16* p2 = baseT + (size_t)r * S_ + c0;
        *(uint4*)&Vt[KSWZ(r, c0)]     = *(const uint4*)p2;
        *(uint4*)&Vt[KSWZ(r, c0 + 8)] = *(const uint4*)(p2 + 8);
    }
    __syncthreads();

    for (int kt = 0; kt < S_ / 64; kt++) {
        // QK^T fused with exp/pack/P-write: only sct[2] (8 regs) live.
#pragma unroll
        for (int t = 0; t < 4; t++) {
            short8 a0 = *(short8*)&Kt[KSWZ(t * 16 + lq, lg * 8)];
            short8 a1 = *(short8*)&Kt[KSWZ(t * 16 + lq, 32 + lg * 8)];
            floatx4 sct[2];
#pragma unroll
            for (int rf = 0; rf < 2; rf++) {
                floatx4 acc = {0, 0, 0, 0};
                acc = __builtin_amdgcn_mfma_f32_16x16x32_bf16(a0, bq[rf][0], acc, 0, 0, 0);
                sct[rf] = __builtin_amdgcn_mfma_f32_16x16x32_bf16(a1, bq[rf][1], acc, 0, 0, 0);
            }
#pragma unroll
            for (int rf = 0; rf < 2; rf++) {
                float p0 = __builtin_amdgcn_exp2f(sct[rf][0]);
                float p1 = __builtin_amdgcn_exp2f(sct[rf][1]);
                float p2 = __builtin_amdgcn_exp2f(sct[rf][2]);
                float p3 = __builtin_amdgcn_exp2f(sct[rf][3]);
                lsum[rf] += (p0 + p1) + (p2 + p3);
                uint2 w;
                w.x = pack_bf16_trunc(p0, p1);
                w.y = pack_bf16_trunc(p2, p3);
                *(uint2*)&Pb[wave][KSWZ(rf * 16 + lq, t * 16 + lg * 4)] = w;
            }
        }

        // per-wave DS in-order: drain P writes before dependent reads
        asm volatile("s_waitcnt lgkmcnt(0)" ::: "memory");

        // O^T += V^T · P^T : A = Vt rows (d), B = Pb rows (q)
        short8 bp[2][2];
#pragma unroll
        for (int rf = 0; rf < 2; rf++) {
            bp[rf][0] = *(short8*)&Pb[wave][KSWZ(rf * 16 + lq, lg * 8)];
            bp[rf][1] = *(short8*)&Pb[wave][KSWZ(rf * 16 + lq, 32 + lg * 8)];
        }
        __builtin_amdgcn_s_setprio(1);
#pragma unroll
        for (int t = 0; t < 4; t++) {
            short8 av0 = *(short8*)&Vt[KSWZ(t * 16 + lq, lg * 8)];
            short8 av1 = *(short8*)&Vt[KSWZ(t * 16 + lq, 32 + lg * 8)];
#pragma unroll
            for (int rf = 0; rf < 2; rf++) {
                oacc[rf][t] = __builtin_amdgcn_mfma_f32_16x16x32_bf16(av0, bp[rf][0], oacc[rf][t], 0, 0, 0);
                oacc[rf][t] = __builtin_amdgcn_mfma_f32_16x16x32_bf16(av1, bp[rf][1], oacc[rf][t], 0, 0, 0);
            }
        }
        __builtin_amdgcn_s_setprio(0);

        __syncthreads();  // all waves done reading Kt/Vt of tile kt
        if (kt < S_ / 64 - 1) {
            const u16* p = base + (size_t)((kt + 1) * 64 + r) * D_ + c0;
            uint4 k0 = *(const uint4*)p;
            uint4 k1 = *(const uint4*)(p + 8);
            const u16* p2 = baseT + (size_t)r * S_ + (kt + 1) * 64 + c0;
            uint4 v0 = *(const uint4*)p2;
            uint4 v1 = *(const uint4*)(p2 + 8);
            *(uint4*)&Kt[KSWZ(r, c0)]     = k0;
            *(uint4*)&Kt[KSWZ(r, c0 + 8)] = k1;
            *(uint4*)&Vt[KSWZ(r, c0)]     = v0;
            *(uint4*)&Vt[KSWZ(r, c0 + 8)] = v1;
        }
        __syncthreads();  // tile kt+1 visible
    }

    // reduce lsum across the 4 lane-quads holding the same q
#pragma unroll
    for (int rf = 0; rf < 2; rf++) {
        lsum[rf] += __shfl_xor(lsum[rf], 16);
        lsum[rf] += __shfl_xor(lsum[rf], 32);
    }
    // epilogue: O^T lane (q=lq, d=16t+4lg+rr) -> aout[b][q][h*64+d] (RNE)
#pragma unroll
    for (int rf = 0; rf < 2; rf++) {
        float inv = 1.0f / fmaxf(lsum[rf], 1e-20f);
        int srow = s0 + wave * 32 + rf * 16 + lq;
        u16* arow = aout + ((size_t)(b * S_ + srow)) * E_ + h * D_;
#pragma unroll
        for (int t = 0; t < 4; t++)
#pragma unroll
            for (int rr = 0; rr < 4; rr++)
                arow[t * 16 + lg * 4 + rr] = f2bf(oacc[rf][t][rr] * inv);
    }
}

// ---------------------------------------------------------------------------
// Kernel 3: out[8192][1024] = AO * Wb^T + bias (fp32 out). Wb bf16 [n][k].
// 128x128 tile per block, 4 waves in 2x2, each wave 64x64 (4x4 C-tiles).
// r9 body + 2D grid; ONLY change: (256,3) reg cap (live ~143 < 170, no
// spill) to guarantee 3 blocks/CU.
// ---------------------------------------------------------------------------
__global__ __launch_bounds__(256, 3) void proj_kernel(const u16* __restrict__ A,
                                                      const u16* __restrict__ Wb,
                                                      const float* __restrict__ bias,
                                                      float* __restrict__ out) {
    int m0   = blockIdx.x * 128;
    int n0   = blockIdx.y * 128;
    int tid  = threadIdx.x;
    int wave = tid >> 6;
    int wm   = wave >> 1;
    int wn   = wave & 1;
    int lane = tid & 63;
    int lq   = lane & 15;
    int lg   = lane >> 4;
    int r    = tid >> 1;
    int c0   = (tid & 1) * 32;

    __shared__ __align__(16) u16 As[128][72];
    __shared__ __align__(16) u16 Bs[128][72];

    floatx4 acc[4][4];
#pragma unroll
    for (int i = 0; i < 4; i++)
#pragma unroll
        for (int j = 0; j < 4; j++) acc[i][j] = (floatx4){0, 0, 0, 0};

    for (int kc = 0; kc < E_; kc += 64) {
        __syncthreads();
        const u16* pa = A + (size_t)(m0 + r) * E_ + kc + c0;
        const u16* pw = Wb + (size_t)(n0 + r) * E_ + kc + c0;
#pragma unroll
        for (int j = 0; j < 4; j++) {
            *(uint4*)&As[r][c0 + j * 8] = *(const uint4*)(pa + j * 8);
            *(uint4*)&Bs[r][c0 + j * 8] = *(const uint4*)(pw + j * 8);
        }
        __syncthreads();

#pragma unroll
        for (int c = 0; c < 2; c++) {
            short8 af[4], bf[4];
#pragma unroll
            for (int i = 0; i < 4; i++)
                af[i] = *(short8*)&As[wm * 64 + i * 16 + lq][c * 32 + lg * 8];
#pragma unroll
            for (int j = 0; j < 4; j++)
                bf[j] = *(short8*)&Bs[wn * 64 + j * 16 + lq][c * 32 + lg * 8];
#pragma unroll
            for (int i = 0; i < 4; i++)
#pragma unroll
                for (int j = 0; j < 4; j++)
                    acc[i][j] = __builtin_amdgcn_mfma_f32_16x16x32_bf16(af[i], bf[j], acc[i][j], 0, 0, 0);
        }
    }

#pragma unroll
    for (int j = 0; j < 4; j++) {
        int nidx = n0 + wn * 64 + j * 16 + lq;
        float bv = bias[nidx];
#pragma unroll
        for (int i = 0; i < 4; i++) {
#pragma unroll
            for (int rr = 0; rr < 4; rr++) {
                int row = m0 + wm * 64 + i * 16 + lg * 4 + rr;
                out[(size_t)row * E_ + nidx] = acc[i][j][rr] + bv;
            }
        }
    }
}

// ---------------------------------------------------------------------------
extern "C" void kernel_launch(void* const* d_in, const int* in_sizes, int n_in,
                              void* d_out, int out_size, void* d_ws, size_t ws_size,
                              hipStream_t stream) {
    const float* x     = (const float*)d_in[0];
    const float* theta = (const float*)d_in[1];
    const float* w_out = (const float*)d_in[2];
    const float* b_out = (const float*)d_in[3];
    float* out = (float*)d_out;

    char* ws = (char*)d_ws;
    const size_t QKV_BYTES = (size_t)B_ * H_ * S_ * D_ * sizeof(u16);  // 16 MiB
    u16* qkv  = (u16*)ws;
    u16* qkvT = (u16*)(ws + QKV_BYTES);
    u16* aout = (u16*)(ws + 2 * QKV_BYTES);
    u16* wbf_safe = (u16*)(ws + 3 * QKV_BYTES);

    prep_kernel<<<3072, 256, 0, stream>>>(x, theta, w_out, qkv, qkvT, wbf_safe);
    attn_kernel<<<(B_ * H_) * (S_ / 128), 256, 0, stream>>>(qkv, qkvT, aout);
    dim3 pg(B_ * S_ / 128, E_ / 128);
    proj_kernel<<<pg, 256, 0, stream>>>(aout, wbf_safe, b_out, out);
}

// Round 13
// 188.183 us; speedup vs baseline: 1.3008x; 1.1816x over previous
//
#include <hip/hip_runtime.h>

// Problem: B=4, S=2048, H=16, D=64, E=1024. Inputs fp32, output fp32.
// out = proj( attention( cos(x+theta) ) )  with Q==K==V per head.
//
// Round 21: attn P-in-register via permlane swaps (VALU, not LDS).
// S^T C-layout word pairs (W[t].x/y at keys 16t+4lg+{0,1}/{2,3}, q=lq)
// redistribute to PV B-frag B[k=8lg+j][n=lq] with exactly:
//   {dst0,dst1} = permlane16_swap(permlane32_swap(W[t],W[t+1]))
// per u32 pair (verified per-lg algebra in journal). Deletes Pb LDS
// (32KB->16KB), 8 ds_write_b64 + 4 ds_read_b128 + lgkmcnt(0) per iter
// (-96 of ~336 LDS-pipe cyc). proj reverted to r9-exact (plain 256 bound;
// r12's (256,3) cost ~25us, likely spill). prep unchanged.
// ws: [0,16M) qkv  [16M,32M) qkvT  [32M,48M) aout  [48M,50M) Wbf.

#define B_  4
#define S_  2048
#define H_  16
#define D_  64
#define E_  1024
// exp(s/8) = exp2(s * log2(e)/8); folded into Q fragments
#define EXP2_SCALE 0.18033688011112043f

typedef unsigned short u16;
typedef unsigned int u32;
typedef __attribute__((ext_vector_type(8))) short short8;
typedef __attribute__((ext_vector_type(4))) float floatx4;

static __device__ __forceinline__ float bf2f(u16 v) {
    return __uint_as_float(((unsigned)v) << 16);
}
static __device__ __forceinline__ u16 f2bf(float f) {
    unsigned u = __float_as_uint(f);
    return (u16)((u + 0x7FFFu + ((u >> 16) & 1u)) >> 16);
}
// pack bf16(lo),bf16(hi) from two f32 by truncation: 1 v_perm_b32
static __device__ __forceinline__ u32 pack_bf16_trunc(float lo, float hi) {
    return __builtin_amdgcn_perm(__float_as_uint(hi), __float_as_uint(lo), 0x07060302u);
}
// unpack-scale-repack a short8 of bf16 by EXP2_SCALE (one-time, RNE)
static __device__ __forceinline__ short8 scale8(short8 v) {
    short8 o;
#pragma unroll
    for (int i = 0; i < 8; i++)
        o[i] = (short)f2bf(bf2f((u16)v[i]) * EXP2_SCALE);
    return o;
}

// XOR-swizzled element offset within a [rows][64] u16 LDS tile.
// Valid for 16B (8-elem) and 8B (4-elem) aligned accesses.
#define KSWZ(r, c) ((((r)) << 6) + (((c) ^ ((((r)) & 7) << 3))))

// ---------------------------------------------------------------------------
// Kernel 1 (fused prep):
//  blocks [0,2048):   qkv[bh][s][d] = cos(x+theta) bf16, qkvT = transpose
//  blocks [2048,3072): Wbf = bf16(W)
// ---------------------------------------------------------------------------
__global__ __launch_bounds__(256) void prep_kernel(const float* __restrict__ x,
                                                   const float* __restrict__ theta,
                                                   const float* __restrict__ W,
                                                   u16* __restrict__ qkv,
                                                   u16* __restrict__ qkvT,
                                                   u16* __restrict__ Wb) {
    __shared__ __align__(16) u16 TQ[64][72];
    int blk = blockIdx.x;
    int tid = threadIdx.x;
    if (blk >= 2048) {  // wconv part
        int i = ((blk - 2048) * 256 + tid) * 4;
        float4 w = *(const float4*)(W + i);
        ushort4 o;
        o.x = f2bf(w.x); o.y = f2bf(w.y); o.z = f2bf(w.z); o.w = f2bf(w.w);
        *(ushort4*)(Wb + i) = o;
        return;
    }
    int stile = blk & 31;
    int bh    = blk >> 5;
    int b     = bh >> 4;
    int h     = bh & 15;
    int i     = tid >> 2;
    int d0    = (tid & 3) << 4;
    int s0    = stile << 6;
    int s     = s0 + i;

    const float* xp = x + ((size_t)(b * S_ + s)) * E_ + h * D_ + d0;
    const float* tp = theta + h * D_ + d0;

    u16 ov[16];
#pragma unroll
    for (int j = 0; j < 16; j += 4) {
        float4 xv = *(const float4*)(xp + j);
        float4 tv = *(const float4*)(tp + j);
        ov[j]     = f2bf(__cosf(xv.x + tv.x));
        ov[j + 1] = f2bf(__cosf(xv.y + tv.y));
        ov[j + 2] = f2bf(__cosf(xv.z + tv.z));
        ov[j + 3] = f2bf(__cosf(xv.w + tv.w));
    }

    u16* qp = qkv + ((size_t)bh * S_ + s) * D_ + d0;
    *(uint4*)qp       = *(uint4*)&ov[0];
    *(uint4*)(qp + 8) = *(uint4*)&ov[8];

#pragma unroll
    for (int j = 0; j < 16; j++) TQ[d0 + j][i] = ov[j];
    __syncthreads();

    int d  = tid >> 2;
    int j0 = (tid & 3) << 4;
    u16 tmp[16];
#pragma unroll
    for (int j = 0; j < 16; j++) tmp[j] = TQ[d][j0 + j];
    u16* qtp = qkvT + ((size_t)bh * D_ + d) * S_ + s0 + j0;
    *(uint4*)qtp       = *(uint4*)&tmp[0];
    *(uint4*)(qtp + 8) = *(uint4*)&tmp[8];
}

// ---------------------------------------------------------------------------
// Kernel 2: flash attention per (bh, 128-q-tile), S^T formulation.
// 4 waves; QK^T fused with exp/pack; P redistributed to PV B-frags via
// v_permlane32_swap + v_permlane16_swap (in-register, no Pb LDS).
// PV: K=32 MFMA, A = Vt rows, B = bp regs. LDS 16KB (Kt+Vt).
// ---------------------------------------------------------------------------
__global__ __launch_bounds__(256, 4) void attn_kernel(const u16* __restrict__ qkv,
                                                      const u16* __restrict__ qkvT,
                                                      u16* __restrict__ aout) {
    int blk0 = blockIdx.x;
    int blk  = (blk0 & 7) * 128 + (blk0 >> 3);
    int qt   = blk & 15;
    int bh   = blk >> 4;
    int b    = bh >> 4;
    int h    = bh & 15;
    int tid  = threadIdx.x;
    int wave = tid >> 6;
    int lane = tid & 63;
    int lq   = lane & 15;
    int lg   = lane >> 4;
    int r    = tid >> 2;
    int c0   = (tid & 3) << 4;

    __shared__ __align__(16) u16 Kt[64 * 64];      // K tile [key][d], swizzled
    __shared__ __align__(16) u16 Vt[64 * 64];      // V^T tile [d][key], swizzled

    const u16* base  = qkv  + (size_t)bh * S_ * D_;
    const u16* baseT = qkvT + (size_t)bh * D_ * S_;
    int s0 = qt * 128;

    short8 bq[2][2];
#pragma unroll
    for (int rf = 0; rf < 2; rf++) {
        const u16* qrow = base + (size_t)(s0 + wave * 32 + rf * 16 + lq) * D_ + lg * 8;
        bq[rf][0] = scale8(*(const short8*)qrow);
        bq[rf][1] = scale8(*(const short8*)(qrow + 32));
    }

    floatx4 oacc[2][4] = {{{0,0,0,0},{0,0,0,0},{0,0,0,0},{0,0,0,0}},
                          {{0,0,0,0},{0,0,0,0},{0,0,0,0},{0,0,0,0}}};
    float lsum[2] = {0.f, 0.f};

    // prologue: stage tile 0
    {
        const u16* p = base + (size_t)r * D_ + c0;
        *(uint4*)&Kt[KSWZ(r, c0)]     = *(const uint4*)p;
        *(uint4*)&Kt[KSWZ(r, c0 + 8)] = *(const uint4*)(p + 8);
        const u16* p2 = baseT + (size_t)r * S_ + c0;
        *(uint4*)&Vt[KSWZ(r, c0)]     = *(const uint4*)p2;
        *(uint4*)&Vt[KSWZ(r, c0 + 8)] = *(const uint4*)(p2 + 8);
    }
    __syncthreads();

    for (int kt = 0; kt < S_ / 64; kt++) {
        // QK^T fused with exp/pack; pairs (t even, t odd) swap into bp frags.
        uint4 bw[2][2];      // bp words [rf][frag]
        u32 pvx[2], pvy[2];  // previous (even-t) packed words per rf
#pragma unroll
        for (int t = 0; t < 4; t++) {
            short8 a0 = *(short8*)&Kt[KSWZ(t * 16 + lq, lg * 8)];
            short8 a1 = *(short8*)&Kt[KSWZ(t * 16 + lq, 32 + lg * 8)];
            floatx4 sct[2];
#pragma unroll
            for (int rf = 0; rf < 2; rf++) {
                floatx4 acc = {0, 0, 0, 0};
                acc = __builtin_amdgcn_mfma_f32_16x16x32_bf16(a0, bq[rf][0], acc, 0, 0, 0);
                sct[rf] = __builtin_amdgcn_mfma_f32_16x16x32_bf16(a1, bq[rf][1], acc, 0, 0, 0);
            }
#pragma unroll
            for (int rf = 0; rf < 2; rf++) {
                float p0 = __builtin_amdgcn_exp2f(sct[rf][0]);
                float p1 = __builtin_amdgcn_exp2f(sct[rf][1]);
                float p2 = __builtin_amdgcn_exp2f(sct[rf][2]);
                float p3 = __builtin_amdgcn_exp2f(sct[rf][3]);
                lsum[rf] += (p0 + p1) + (p2 + p3);
                u32 wx = pack_bf16_trunc(p0, p1);
                u32 wy = pack_bf16_trunc(p2, p3);
                if ((t & 1) == 0) {
                    pvx[rf] = wx;
                    pvy[rf] = wy;
                } else {
                    // {dst0,dst1} = swap16(swap32(W[even], W[odd])) per word
                    u32 d0x = pvx[rf], d1x = wx;
                    asm("v_permlane32_swap_b32 %0, %1" : "+v"(d0x), "+v"(d1x));
                    asm("v_permlane16_swap_b32 %0, %1" : "+v"(d0x), "+v"(d1x));
                    u32 d0y = pvy[rf], d1y = wy;
                    asm("v_permlane32_swap_b32 %0, %1" : "+v"(d0y), "+v"(d1y));
                    asm("v_permlane16_swap_b32 %0, %1" : "+v"(d0y), "+v"(d1y));
                    // bp frag words m=0..3 = [dst0(x), dst0(y), dst1(x), dst1(y)]
                    bw[rf][t >> 1] = (uint4){d0x, d0y, d1x, d1y};
                }
            }
        }

        // O^T += V^T · P^T : A = Vt rows (d), B = bp (registers)
        __builtin_amdgcn_s_setprio(1);
#pragma unroll
        for (int t = 0; t < 4; t++) {
            short8 av0 = *(short8*)&Vt[KSWZ(t * 16 + lq, lg * 8)];
            short8 av1 = *(short8*)&Vt[KSWZ(t * 16 + lq, 32 + lg * 8)];
#pragma unroll
            for (int rf = 0; rf < 2; rf++) {
                short8 bp0 = __builtin_bit_cast(short8, bw[rf][0]);
                short8 bp1 = __builtin_bit_cast(short8, bw[rf][1]);
                oacc[rf][t] = __builtin_amdgcn_mfma_f32_16x16x32_bf16(av0, bp0, oacc[rf][t], 0, 0, 0);
                oacc[rf][t] = __builtin_amdgcn_mfma_f32_16x16x32_bf16(av1, bp1, oacc[rf][t], 0, 0, 0);
            }
        }
        __builtin_amdgcn_s_setprio(0);

        __syncthreads();  // all waves done reading Kt/Vt of tile kt
        if (kt < S_ / 64 - 1) {
            const u16* p = base + (size_t)((kt + 1) * 64 + r) * D_ + c0;
            uint4 k0 = *(const uint4*)p;
            uint4 k1 = *(const uint4*)(p + 8);
            const u16* p2 = baseT + (size_t)r * S_ + (kt + 1) * 64 + c0;
            uint4 v0 = *(const uint4*)p2;
            uint4 v1 = *(const uint4*)(p2 + 8);
            *(uint4*)&Kt[KSWZ(r, c0)]     = k0;
            *(uint4*)&Kt[KSWZ(r, c0 + 8)] = k1;
            *(uint4*)&Vt[KSWZ(r, c0)]     = v0;
            *(uint4*)&Vt[KSWZ(r, c0 + 8)] = v1;
        }
        __syncthreads();  // tile kt+1 visible
    }

    // reduce lsum across the 4 lane-quads holding the same q
#pragma unroll
    for (int rf = 0; rf < 2; rf++) {
        lsum[rf] += __shfl_xor(lsum[rf], 16);
        lsum[rf] += __shfl_xor(lsum[rf], 32);
    }
    // epilogue: O^T lane (q=lq, d=16t+4lg+rr) -> aout[b][q][h*64+d] (RNE)
#pragma unroll
    for (int rf = 0; rf < 2; rf++) {
        float inv = 1.0f / fmaxf(lsum[rf], 1e-20f);
        int srow = s0 + wave * 32 + rf * 16 + lq;
        u16* arow = aout + ((size_t)(b * S_ + srow)) * E_ + h * D_;
#pragma unroll
        for (int t = 0; t < 4; t++)
#pragma unroll
            for (int rr = 0; rr < 4; rr++)
                arow[t * 16 + lg * 4 + rr] = f2bf(oacc[rf][t][rr] * inv);
    }
}

// ---------------------------------------------------------------------------
// Kernel 3: out[8192][1024] = AO * Wb^T + bias (fp32 out). Wb bf16 [n][k].
// 128x128 tile per block, 4 waves in 2x2, each wave 64x64 (4x4 C-tiles).
// == r9-exact (plain 256 bound; r12's (256,3) regressed ~25us).
// ---------------------------------------------------------------------------
__global__ __launch_bounds__(256) void proj_kernel(const u16* __restrict__ A,
                                                   const u16* __restrict__ Wb,
                                                   const float* __restrict__ bias,
                                                   float* __restrict__ out) {
    int m0   = blockIdx.x * 128;
    int n0   = blockIdx.y * 128;
    int tid  = threadIdx.x;
    int wave = tid >> 6;
    int wm   = wave >> 1;
    int wn   = wave & 1;
    int lane = tid & 63;
    int lq   = lane & 15;
    int lg   = lane >> 4;
    int r    = tid >> 1;
    int c0   = (tid & 1) * 32;

    __shared__ __align__(16) u16 As[128][72];
    __shared__ __align__(16) u16 Bs[128][72];

    floatx4 acc[4][4];
#pragma unroll
    for (int i = 0; i < 4; i++)
#pragma unroll
        for (int j = 0; j < 4; j++) acc[i][j] = (floatx4){0, 0, 0, 0};

    for (int kc = 0; kc < E_; kc += 64) {
        __syncthreads();
        const u16* pa = A + (size_t)(m0 + r) * E_ + kc + c0;
        const u16* pw = Wb + (size_t)(n0 + r) * E_ + kc + c0;
#pragma unroll
        for (int j = 0; j < 4; j++) {
            *(uint4*)&As[r][c0 + j * 8] = *(const uint4*)(pa + j * 8);
            *(uint4*)&Bs[r][c0 + j * 8] = *(const uint4*)(pw + j * 8);
        }
        __syncthreads();

#pragma unroll
        for (int c = 0; c < 2; c++) {
            short8 af[4], bf[4];
#pragma unroll
            for (int i = 0; i < 4; i++)
                af[i] = *(short8*)&As[wm * 64 + i * 16 + lq][c * 32 + lg * 8];
#pragma unroll
            for (int j = 0; j < 4; j++)
                bf[j] = *(short8*)&Bs[wn * 64 + j * 16 + lq][c * 32 + lg * 8];
#pragma unroll
            for (int i = 0; i < 4; i++)
#pragma unroll
                for (int j = 0; j < 4; j++)
                    acc[i][j] = __builtin_amdgcn_mfma_f32_16x16x32_bf16(af[i], bf[j], acc[i][j], 0, 0, 0);
        }
    }

#pragma unroll
    for (int j = 0; j < 4; j++) {
        int nidx = n0 + wn * 64 + j * 16 + lq;
        float bv = bias[nidx];
#pragma unroll
        for (int i = 0; i < 4; i++) {
#pragma unroll
            for (int rr = 0; rr < 4; rr++) {
                int row = m0 + wm * 64 + i * 16 + lg * 4 + rr;
                out[(size_t)row * E_ + nidx] = acc[i][j][rr] + bv;
            }
        }
    }
}

// ---------------------------------------------------------------------------
extern "C" void kernel_launch(void* const* d_in, const int* in_sizes, int n_in,
                              void* d_out, int out_size, void* d_ws, size_t ws_size,
                              hipStream_t stream) {
    const float* x     = (const float*)d_in[0];
    const float* theta = (const float*)d_in[1];
    const float* w_out = (const float*)d_in[2];
    const float* b_out = (const float*)d_in[3];
    float* out = (float*)d_out;

    char* ws = (char*)d_ws;
    const size_t QKV_BYTES = (size_t)B_ * H_ * S_ * D_ * sizeof(u16);  // 16 MiB
    u16* qkv  = (u16*)ws;
    u16* qkvT = (u16*)(ws + QKV_BYTES);
    u16* aout = (u16*)(ws + 2 * QKV_BYTES);
    u16* wbf_safe = (u16*)(ws + 3 * QKV_BYTES);

    prep_kernel<<<3072, 256, 0, stream>>>(x, theta, w_out, qkv, qkvT, wbf_safe);
    attn_kernel<<<(B_ * H_) * (S_ / 128), 256, 0, stream>>>(qkv, qkvT, aout);
    dim3 pg(B_ * S_ / 128, E_ / 128);
    proj_kernel<<<pg, 256, 0, stream>>>(aout, wbf_safe, b_out, out);
}